// Round 5
// baseline (875.134 us; speedup 1.0000x reference)
//
#include <hip/hip_runtime.h>
#include <math.h>

#define N 96
#define PAD 100        // padded LDS row stride (floats)
#define T 768          // 12 waves per block
#define NB 4           // blocks (4 CUs); M rows 24 per block
#define BROWS 24
#define ITERS 50

// Multi-CU fused MPM.
// Per iter: block bc computes M[j,:] for j in [24bc,24bc+24) from LDS-local X,
// writes slice to global Mg[it&1], grid-barrier, stages full M to LDS, then
// REDUNDANTLY aggregates all 96 rows + norm + X update (bitwise identical in
// every block -> X stays consistent with no second exchange/barrier).
// Thread maps:
//   M-phase:  t=(p<<2)|q : q=b-quarter, ap=p%48 -> cols a0=2ap,a0+1, g=p/48,
//             rows jl = 4*jj+g (jj=0..5); W[a0..a0+1][24q..24q+23] in 48 VGPRs.
//   agg:      col a=t%96 fixed, rows i = t/96 + 8k (k=0..11).
__global__ __launch_bounds__(T, 1) void k_fused(const float* __restrict__ A,
                                                const float* __restrict__ vec,
                                                float* __restrict__ out,
                                                float* __restrict__ Mg,   // 2*96*96
                                                int* __restrict__ ctr) {  // ITERS
    __shared__ float Xs[N * PAD];          // 38400 B : X (staging for B, then A)
    __shared__ float Ms[N * PAD];          // 38400 B : staged full M
    __shared__ unsigned char lst[N * 48];  //  4608 B : neighbor lists (ascending)
    __shared__ short cnt[N];
    __shared__ float degA[N];
    __shared__ float degB[N];
    __shared__ float red[T / 64];

    const int t = threadIdx.x;
    const int bc = blockIdx.x;
    const int q = t & 3;                   // b-quarter
    const int p = t >> 2;
    const int ap = p % 48;                 // column-pair id
    const int g = p / 48;                  // row group 0..3
    const int a0 = 2 * ap;
    const int a = t % N;                   // aggregate column
    const int i0 = t / N;                  // aggregate row base
    const float s1 = 1.0f / (1.0f + expf(-1.0f));   // sigmoid(1) = diag of B
    const float s1s1 = s1 * s1;

    // ---- setup (redundant per block, all block-local) ----
    // phase 0: B -> Xs (staging)
#pragma unroll
    for (int k = 0; k < 12; ++k) {
        int e = t + k * T;
        int r = e / N, c = e % N;
        float logit;
        if (r == c) {
            logit = 1.0f;
        } else {
            int i = r < c ? r : c;
            int j = r < c ? c : r;
            int idx = i * 95 - (i * (i - 1)) / 2 + (j - i - 1);
            logit = vec[idx];
        }
        Xs[r * PAD + c] = 1.0f / (1.0f + expf(-logit));
    }
    __syncthreads();

    // W quarter-columns into registers (B symmetric), diag=0
    float Wr0[24], Wr1[24];
#pragma unroll
    for (int bb = 0; bb < 24; ++bb) {
        int b = 24 * q + bb;
        float w0 = Xs[b * PAD + a0] * s1s1;
        float w1 = Xs[b * PAD + a0 + 1] * s1s1;
        if (b == a0) w0 = 0.0f;
        if (b == a0 + 1) w1 = 0.0f;
        Wr0[bb] = w0;
        Wr1[bb] = w1;
    }

    if (t < N) {
        float s = 0.f;
        for (int r = 0; r < N; ++r) s += Xs[r * PAD + t];
        degB[t] = s;
    }
    __syncthreads();   // all reads of B done

    // phase 1: A -> Xs (staging)
#pragma unroll
    for (int k = 0; k < 12; ++k) {
        int e = t + k * T;
        Xs[(e / N) * PAD + (e % N)] = A[e];
    }
    __syncthreads();

    if (t < N) {
        float s = 0.f;
        for (int r = 0; r < N; ++r) s += Xs[r * PAD + t];   // A symmetric
        degA[t] = s;
    } else if (t < 2 * N) {
        int i = t - N;
        int c_ = 0;
        for (int j = 0; j < N; ++j) {
            if (j != i && Xs[j * PAD + i] > 0.5f)            // A symmetric
                lst[i * 48 + c_++] = (unsigned char)j;
        }
        cnt[i] = (short)c_;
    }
    __syncthreads();   // lists/degs ready, Xs(A) reads done

    // node-sim coefficients for this thread's 12 aggregate elements
    float ns_reg[12];
#pragma unroll
    for (int k = 0; k < 12; ++k) {
        int i = i0 + 8 * k;
        ns_reg[k] = s1 / (fabsf(degA[i] - degB[a]) + 1.0f);
    }

    // X0 = 1/96 everywhere (||X0|| = 1 exactly)
#pragma unroll
    for (int k = 0; k < 12; ++k) {
        int e = t + k * T;
        Xs[(e / N) * PAD + (e % N)] = (1.0f / 96.0f);
    }
    __syncthreads();

    // ---- main loop ----
    for (int it = 0; it < ITERS; ++it) {
        float* Mbuf = Mg + (it & 1) * (N * N);

        // M-phase: own 24 rows (j = 24bc + 4jj + g)
        for (int jj = 0; jj < 6; ++jj) {
            int j = BROWS * bc + 4 * jj + g;
            const float* xr = &Xs[j * PAD + 24 * q];
            float m0 = 0.f, m1 = 0.f;
#pragma unroll
            for (int c = 0; c < 6; ++c) {
                float4 x = *(const float4*)(xr + 4 * c);
                m0 = fmaxf(fmaxf(m0, Wr0[4 * c + 0] * x.x), Wr0[4 * c + 1] * x.y);
                m0 = fmaxf(fmaxf(m0, Wr0[4 * c + 2] * x.z), Wr0[4 * c + 3] * x.w);
                m1 = fmaxf(fmaxf(m1, Wr1[4 * c + 0] * x.x), Wr1[4 * c + 1] * x.y);
                m1 = fmaxf(fmaxf(m1, Wr1[4 * c + 2] * x.z), Wr1[4 * c + 3] * x.w);
            }
            m0 = fmaxf(m0, __shfl_xor(m0, 1, 64));
            m0 = fmaxf(m0, __shfl_xor(m0, 2, 64));
            m1 = fmaxf(m1, __shfl_xor(m1, 1, 64));
            m1 = fmaxf(m1, __shfl_xor(m1, 2, 64));
            if (q == 0)
                *(float2*)&Mbuf[j * N + a0] = make_float2(m0, m1);
        }

        // ---- grid barrier (release -> arrive -> spin -> acquire) ----
        __threadfence();                   // drain + write back own M slice
        __syncthreads();
        if (t == 0) {
            __hip_atomic_fetch_add(&ctr[it], 1, __ATOMIC_ACQ_REL,
                                   __HIP_MEMORY_SCOPE_AGENT);
            while (__hip_atomic_load(&ctr[it], __ATOMIC_ACQUIRE,
                                     __HIP_MEMORY_SCOPE_AGENT) < NB)
                __builtin_amdgcn_s_sleep(1);
        }
        __syncthreads();
        __threadfence();                   // invalidate caches before reading M

        // stage full M into LDS (coalesced float4)
        const float4* M4 = (const float4*)Mbuf;
#pragma unroll
        for (int k = 0; k < 3; ++k) {
            int v = t + k * T;             // float4 index 0..2303
            int r = v / 24;
            int c = 4 * (v % 24);
            *(float4*)&Ms[r * PAD + c] = M4[v];
        }
        __syncthreads();

        // aggregate ALL rows redundantly (diag first, then ascending j)
        float y[12];
#pragma unroll
        for (int k = 0; k < 12; ++k) {
            int i = i0 + 8 * k;
            float acc = Xs[i * PAD + a] * ns_reg[k];
            int nc = cnt[i];
            const unsigned char* li = &lst[i * 48];
            for (int qq = 0; qq < nc; ++qq)
                acc += Ms[(int)li[qq] * PAD + a];
            y[k] = acc;
        }

        // block-wide norm (deterministic fixed tree -> identical in all blocks)
        float ss = 0.f;
#pragma unroll
        for (int k = 0; k < 12; ++k) ss = fmaf(y[k], y[k], ss);
#pragma unroll
        for (int mm = 1; mm < 64; mm <<= 1) ss += __shfl_xor(ss, mm, 64);
        if ((t & 63) == 0) red[t >> 6] = ss;
        __syncthreads();
        float s = 0.f;
#pragma unroll
        for (int w = 0; w < T / 64; ++w) s += red[w];
        float inv = 1.0f / sqrtf(s);
#pragma unroll
        for (int k = 0; k < 12; ++k)
            Xs[(i0 + 8 * k) * PAD + a] = y[k] * inv;
        __syncthreads();                   // X ready for next iter
    }

    // ---- output (block 0 only; every block holds the full final X) ----
    if (bc == 0) {
#pragma unroll
        for (int k = 0; k < 12; ++k) {
            int e = t + k * T;
            out[e] = Xs[(e / N) * PAD + (e % N)];
        }
    }
}

extern "C" void kernel_launch(void* const* d_in, const int* in_sizes, int n_in,
                              void* d_out, int out_size, void* d_ws, size_t ws_size,
                              hipStream_t stream) {
    const float* A = (const float*)d_in[0];     // A_gt, 96*96
    const float* vec = (const float*)d_in[1];   // vec_logits, 4560
    float* out = (float*)d_out;
    int* ctr = (int*)d_ws;                      // [0,256): barrier counters
    float* Mg = (float*)((char*)d_ws + 256);    // 2*96*96 floats exchange
    hipMemsetAsync(d_ws, 0, 256, stream);       // zero counters (capture-safe)
    k_fused<<<NB, T, 0, stream>>>(A, vec, out, Mg, ctr);
}

// Round 6
// 872.076 us; speedup vs baseline: 1.0035x; 1.0035x over previous
//
#include <hip/hip_runtime.h>
#include <math.h>

#define N 96
#define PAD 100        // padded LDS row stride (floats)
#define T 768          // 12 waves, one workgroup, one CU
#define ITERS 50

typedef float f2 __attribute__((ext_vector_type(2)));

// packed fp32 multiply (VOP3P) — guarantees 2 muls / instr
__device__ __forceinline__ f2 pkmul(f2 a, f2 b) {
    f2 d;
    asm("v_pk_mul_f32 %0, %1, %2" : "=v"(d) : "v"(a), "v"(b));
    return d;
}

// Fully fused MPM, one workgroup.
// M-phase map: t = g*192 + cg*8 + q ; g=row group (j≡g mod 4, 24 rows),
//   cg=col quad (a in [4cg,4cg+4)), q=b-eighth (b in [12q,12q+12)).
//   W[4 cols][12 b] lives in 24 float2 VGPRs (48 regs — safe size).
//   Per row: 3 ds_read_b128 + 24 pk_mul + 24 max3, then recursive-halving
//   combine over the 8 q-lanes (4 shfl+4 max), lane q&1==0 writes col
//   4cg+2*((q>>2)&1)+((q>>1)&1) of Ms.
// Agg map:   a = t%96, rows i = t/96 + 8k (k=0..11). Diag X held in regs.
__global__ __launch_bounds__(T, 1) void k_fused(const float* __restrict__ A,
                                                const float* __restrict__ vec,
                                                float* __restrict__ out) {
    __shared__ float Xs[N * PAD];          // 38400 B : X (staging for B, then A)
    __shared__ float Ms[N * PAD];          // 38400 B : full M
    __shared__ unsigned char lst[N * 48];  //  4608 B : neighbor lists (ascending)
    __shared__ short cnt[N];
    __shared__ float degA[N];
    __shared__ float degB[N];
    __shared__ float red[T / 64];

    const int t = threadIdx.x;
    const int g  = t / 192;                // row group 0..3 (wave-uniform)
    const int r  = t % 192;
    const int q  = r & 7;                  // b-eighth
    const int cg = r >> 3;                 // col quad 0..23
    const int sel2 = (q >> 2) & 1;
    const int sel1 = (q >> 1) & 1;
    const int mcol = 4 * cg + 2 * sel2 + sel1;
    const int a  = t % N;                  // agg column
    const int i0 = t / N;                  // agg row base 0..7
    const float s1 = 1.0f / (1.0f + expf(-1.0f));   // sigmoid(1) = diag of B
    const float s1s1 = s1 * s1;

    // ---- setup phase 0: B -> Xs (staging) ----
#pragma unroll
    for (int k = 0; k < 12; ++k) {
        int e = t + k * T;
        int rr = e / N, cc = e % N;
        float logit;
        if (rr == cc) {
            logit = 1.0f;
        } else {
            int i = rr < cc ? rr : cc;
            int j = rr < cc ? cc : rr;
            int idx = i * 95 - (i * (i - 1)) / 2 + (j - i - 1);
            logit = vec[idx];
        }
        Xs[rr * PAD + cc] = 1.0f / (1.0f + expf(-logit));
    }
    __syncthreads();

    // W tiles into registers (B symmetric: col a == row a), diag = 0
    f2 W2[24];
#pragma unroll
    for (int c = 0; c < 4; ++c) {
        int ac = 4 * cg + c;
#pragma unroll
        for (int bp = 0; bp < 6; ++bp) {
            int b0 = 12 * q + 2 * bp;
            float w0 = (b0 == ac) ? 0.f : Xs[b0 * PAD + ac] * s1s1;
            float w1 = (b0 + 1 == ac) ? 0.f : Xs[(b0 + 1) * PAD + ac] * s1s1;
            W2[c * 6 + bp] = (f2){w0, w1};
        }
    }

    if (t < N) {
        float s = 0.f;
        for (int rr = 0; rr < N; ++rr) s += Xs[rr * PAD + t];
        degB[t] = s;
    }
    __syncthreads();   // all reads of B done

    // ---- setup phase 1: A -> Xs (staging) ----
#pragma unroll
    for (int k = 0; k < 12; ++k) {
        int e = t + k * T;
        Xs[(e / N) * PAD + (e % N)] = A[e];
    }
    __syncthreads();

    if (t < N) {
        float s = 0.f;
        for (int rr = 0; rr < N; ++rr) s += Xs[rr * PAD + t];   // A symmetric
        degA[t] = s;
    } else if (t < 2 * N) {
        int i = t - N;
        int c_ = 0;
        for (int j = 0; j < N; ++j) {
            if (j != i && Xs[j * PAD + i] > 0.5f)                // A symmetric
                lst[i * 48 + c_++] = (unsigned char)j;
        }
        cnt[i] = (short)c_;
    }
    __syncthreads();   // lists/degs ready, Xs(A) reads done

    // node-sim coefficients + register-resident X for the agg map
    float ns_reg[12], xreg[12];
#pragma unroll
    for (int k = 0; k < 12; ++k) {
        int i = i0 + 8 * k;
        ns_reg[k] = s1 / (fabsf(degA[i] - degB[a]) + 1.0f);
        xreg[k] = (1.0f / 96.0f);
    }

    // X0 = 1/96 everywhere (||X0|| = 1 exactly)
#pragma unroll
    for (int k = 0; k < 12; ++k) {
        int e = t + k * T;
        Xs[(e / N) * PAD + (e % N)] = (1.0f / 96.0f);
    }
    __syncthreads();

    // ---- main loop ----
    for (int it = 0; it < ITERS; ++it) {
        // M-phase: 24 rows j = 4*jj+g
#pragma unroll 4
        for (int jj = 0; jj < 24; ++jj) {
            int j = 4 * jj + g;
            const float* xr = &Xs[j * PAD + 12 * q];
            float4 xA = *(const float4*)(xr);
            float4 xB = *(const float4*)(xr + 4);
            float4 xC = *(const float4*)(xr + 8);
            f2 xp[6];
            xp[0] = (f2){xA.x, xA.y}; xp[1] = (f2){xA.z, xA.w};
            xp[2] = (f2){xB.x, xB.y}; xp[3] = (f2){xB.z, xB.w};
            xp[4] = (f2){xC.x, xC.y}; xp[5] = (f2){xC.z, xC.w};
            float m[4] = {0.f, 0.f, 0.f, 0.f};
#pragma unroll
            for (int c = 0; c < 4; ++c) {
#pragma unroll
                for (int bp = 0; bp < 6; ++bp) {
                    f2 p = pkmul(W2[c * 6 + bp], xp[bp]);
                    m[c] = fmaxf(fmaxf(m[c], p.x), p.y);   // v_max3_f32
                }
            }
            // recursive-halving combine over the 8 q-lanes (exact max)
            float kA = sel2 ? m[2] : m[0];
            float kB = sel2 ? m[3] : m[1];
            float sA = sel2 ? m[0] : m[2];
            float sB = sel2 ? m[1] : m[3];
            float u0 = fmaxf(kA, __shfl_xor(sA, 4, 64));
            float u1 = fmaxf(kB, __shfl_xor(sB, 4, 64));
            float kC = sel1 ? u1 : u0;
            float sC = sel1 ? u0 : u1;
            float v  = fmaxf(kC, __shfl_xor(sC, 2, 64));
            float w  = fmaxf(v, __shfl_xor(v, 1, 64));
            if (!(q & 1)) Ms[j * PAD + mcol] = w;
        }
        __syncthreads();   // Ms complete

        // aggregate (diag from regs, then ascending-j neighbors — exact order)
        float y[12];
#pragma unroll
        for (int k = 0; k < 12; ++k) y[k] = xreg[k] * ns_reg[k];
#pragma unroll
        for (int k = 0; k < 12; ++k) {
            int i = i0 + 8 * k;
            int nc = cnt[i];
            const unsigned char* li = &lst[i * 48];
            float acc = y[k];
            for (int qq = 0; qq < nc; ++qq)
                acc += Ms[(int)li[qq] * PAD + a];
            y[k] = acc;
        }

        // block-wide norm (deterministic fixed tree, identical to prior rounds)
        float ss = 0.f;
#pragma unroll
        for (int k = 0; k < 12; ++k) ss = fmaf(y[k], y[k], ss);
#pragma unroll
        for (int mm = 1; mm < 64; mm <<= 1) ss += __shfl_xor(ss, mm, 64);
        if ((t & 63) == 0) red[t >> 6] = ss;
        __syncthreads();   // red ready (Ms reads also done)
        float s = 0.f;
#pragma unroll
        for (int w2 = 0; w2 < T / 64; ++w2) s += red[w2];
        float inv = 1.0f / sqrtf(s);
#pragma unroll
        for (int k = 0; k < 12; ++k) {
            xreg[k] = y[k] * inv;
            Xs[(i0 + 8 * k) * PAD + a] = xreg[k];
        }
        __syncthreads();   // X ready for next iter
    }

    // ---- output ----
#pragma unroll
    for (int k = 0; k < 12; ++k) {
        int e = t + k * T;
        out[e] = Xs[(e / N) * PAD + (e % N)];
    }
}

extern "C" void kernel_launch(void* const* d_in, const int* in_sizes, int n_in,
                              void* d_out, int out_size, void* d_ws, size_t ws_size,
                              hipStream_t stream) {
    const float* A = (const float*)d_in[0];     // A_gt, 96*96
    const float* vec = (const float*)d_in[1];   // vec_logits, 4560
    float* out = (float*)d_out;
    k_fused<<<1, T, 0, stream>>>(A, vec, out);
}

// Round 8
// 647.390 us; speedup vs baseline: 1.3518x; 1.3471x over previous
//
#include <hip/hip_runtime.h>
#include <math.h>

#define N 96
#define PAD 100        // padded LDS row stride (floats)
#define T 768          // 12 waves, one workgroup, one CU
#define ITERS 50
#define LW 52          // neighbor-list width (u16 entries, padded to x4)

typedef unsigned short u16x4 __attribute__((ext_vector_type(4)));

// quad-lane max via DPP (VALU pipe, no LDS traffic); CTRL must be constexpr
template <int CTRL>
__device__ __forceinline__ float dppmax(float m) {
    int mi = __builtin_bit_cast(int, m);
    int sw = __builtin_amdgcn_update_dpp(mi, mi, CTRL, 0xf, 0xf, true);
    return fmaxf(m, __builtin_bit_cast(float, sw));
}
#define DPP_XOR1 0xB1  // quad_perm:[1,0,3,2]
#define DPP_XOR2 0x4E  // quad_perm:[2,3,0,1]

// Fully fused MPM, one workgroup (round-4 map + DPP combine + 3 barriers/iter).
// M-phase: t=(p<<2)|q : q=b-quarter (24 b), ap=p%48 -> cols a0=2ap,a0+1,
//          g=p/48 -> rows j≡g (mod 4), 24 rows. W[2][24] in 48 VGPRs.
// Agg:     a=t%96, rows i=t/96+8k (k=0..11); diag X register-resident.
__global__ __launch_bounds__(T, 1) void k_fused(const float* __restrict__ A,
                                                const float* __restrict__ vec,
                                                float* __restrict__ out) {
    __shared__ float Xs[N * PAD];            // 38400 B : X (staging B, then A)
    __shared__ float Ms[(N + 1) * PAD];      // 38800 B : full M + zero row 96
    __shared__ unsigned short lst[N * LW];   //  9984 B : nbr float-index offsets
    __shared__ short cnt4[N];                // padded counts (multiple of 4)
    __shared__ float degA[N];
    __shared__ float degB[N];
    __shared__ float red[T / 64];

    const int t = threadIdx.x;
    const int q = t & 3;                   // b-quarter
    const int p = t >> 2;
    const int ap = p % 48;                 // column-pair id
    const int g = p / 48;                  // row group 0..3
    const int a0 = 2 * ap;
    const int a = t % N;                   // agg column
    const int i0 = t / N;                  // agg row base 0..7
    const float s1 = 1.0f / (1.0f + expf(-1.0f));   // sigmoid(1) = diag of B
    const float s1s1 = s1 * s1;

    // ---- setup phase 0: B -> Xs (staging) ----
#pragma unroll
    for (int k = 0; k < 12; ++k) {
        int e = t + k * T;
        int r = e / N, c = e % N;
        float logit;
        if (r == c) {
            logit = 1.0f;
        } else {
            int i = r < c ? r : c;
            int j = r < c ? c : r;
            int idx = i * 95 - (i * (i - 1)) / 2 + (j - i - 1);
            logit = vec[idx];
        }
        Xs[r * PAD + c] = 1.0f / (1.0f + expf(-logit));
    }
    __syncthreads();

    // W quarter-columns into registers (B symmetric: col a == row a), diag=0
    float Wr0[24], Wr1[24];
#pragma unroll
    for (int bb = 0; bb < 24; ++bb) {
        int b = 24 * q + bb;
        float w0 = Xs[b * PAD + a0] * s1s1;
        float w1 = Xs[b * PAD + a0 + 1] * s1s1;
        if (b == a0) w0 = 0.0f;
        if (b == a0 + 1) w1 = 0.0f;
        Wr0[bb] = w0;
        Wr1[bb] = w1;
    }

    if (t < N) {
        float s = 0.f;
        for (int r = 0; r < N; ++r) s += Xs[r * PAD + t];
        degB[t] = s;
    }
    __syncthreads();   // all reads of B done

    // ---- setup phase 1: A -> Xs (staging) ----
#pragma unroll
    for (int k = 0; k < 12; ++k) {
        int e = t + k * T;
        Xs[(e / N) * PAD + (e % N)] = A[e];
    }
    __syncthreads();

    if (t < N) {
        float s = 0.f;
        for (int r = 0; r < N; ++r) s += Xs[r * PAD + t];   // A symmetric
        degA[t] = s;
    } else if (t < 2 * N) {
        int i = t - N;
        int c_ = 0;
        for (int j = 0; j < N; ++j) {
            if (j != i && Xs[j * PAD + i] > 0.5f)            // A symmetric
                lst[i * LW + c_++] = (unsigned short)(j * PAD);
        }
        while (c_ & 3) lst[i * LW + c_++] = (unsigned short)(N * PAD); // zero row
        cnt4[i] = (short)c_;
    }
    // zero row 96 of Ms (pad target) — written once, never overwritten
    if (t < PAD) Ms[N * PAD + t] = 0.0f;
    __syncthreads();   // lists/degs ready, Xs(A) reads done

    // node-sim coefficients + register-resident diag X for the agg map
    float ns_reg[12], xreg[12];
#pragma unroll
    for (int k = 0; k < 12; ++k) {
        int i = i0 + 8 * k;
        ns_reg[k] = s1 / (fabsf(degA[i] - degB[a]) + 1.0f);
        xreg[k] = (1.0f / 96.0f);
    }

    // X0 = 1/96 everywhere (||X0|| = 1 exactly)
#pragma unroll
    for (int k = 0; k < 12; ++k) {
        int e = t + k * T;
        Xs[(e / N) * PAD + (e % N)] = (1.0f / 96.0f);
    }
    __syncthreads();

    const float* xbase = &Xs[g * PAD + 24 * q];   // row jj -> + jj*4*PAD
    const float* Msa = Ms + a;

    // ---- main loop ----
    for (int it = 0; it < ITERS; ++it) {
        // M-phase: 24 rows j = 4*jj + g, const-offset ds reads
#pragma unroll 6
        for (int jj = 0; jj < 24; ++jj) {
            const float* xr = xbase + jj * 4 * PAD;
            float m0 = 0.f, m1 = 0.f;
#pragma unroll
            for (int c = 0; c < 6; ++c) {
                float4 x = *(const float4*)(xr + 4 * c);
                m0 = fmaxf(fmaxf(m0, Wr0[4 * c + 0] * x.x), Wr0[4 * c + 1] * x.y);
                m0 = fmaxf(fmaxf(m0, Wr0[4 * c + 2] * x.z), Wr0[4 * c + 3] * x.w);
                m1 = fmaxf(fmaxf(m1, Wr1[4 * c + 0] * x.x), Wr1[4 * c + 1] * x.y);
                m1 = fmaxf(fmaxf(m1, Wr1[4 * c + 2] * x.z), Wr1[4 * c + 3] * x.w);
            }
            // combine b-quarters across the lane quad on the VALU pipe (exact)
            m0 = dppmax<DPP_XOR1>(m0);
            m0 = dppmax<DPP_XOR2>(m0);
            m1 = dppmax<DPP_XOR1>(m1);
            m1 = dppmax<DPP_XOR2>(m1);
            if (q == 0)
                *(float2*)&Ms[(4 * jj + g) * PAD + a0] = make_float2(m0, m1);
        }
        __syncthreads();   // (A) Ms complete; all Xs reads done

        // aggregate (diag from regs, then ascending-j neighbors — exact order)
        float y[12];
#pragma unroll
        for (int k = 0; k < 12; ++k) {
            int i = i0 + 8 * k;
            float acc = xreg[k] * ns_reg[k];
            int nch = (int)cnt4[i] >> 2;
            const unsigned short* lp = &lst[i * LW];
            for (int cc = 0; cc < nch; ++cc) {
                u16x4 o = *(const u16x4*)(lp + 4 * cc);
                acc += Msa[(int)o.x];
                acc += Msa[(int)o.y];
                acc += Msa[(int)o.z];
                acc += Msa[(int)o.w];
            }
            y[k] = acc;
        }

        // block-wide norm (deterministic fixed tree, identical to prior rounds)
        float ss = 0.f;
#pragma unroll
        for (int k = 0; k < 12; ++k) ss = fmaf(y[k], y[k], ss);
#pragma unroll
        for (int mm = 1; mm < 64; mm <<= 1) ss += __shfl_xor(ss, mm, 64);
        if ((t & 63) == 0) red[t >> 6] = ss;
        __syncthreads();   // (B) red ready; all Ms reads done
        float s = 0.f;
#pragma unroll
        for (int w2 = 0; w2 < T / 64; ++w2) s += red[w2];
        float inv = 1.0f / sqrtf(s);
#pragma unroll
        for (int k = 0; k < 12; ++k) {
            xreg[k] = y[k] * inv;
            Xs[(i0 + 8 * k) * PAD + a] = xreg[k];
        }
        __syncthreads();   // (C) Xs ready for next iter; Ms safe to overwrite
    }

    // ---- output ----
#pragma unroll
    for (int k = 0; k < 12; ++k) {
        int e = t + k * T;
        out[e] = Xs[(e / N) * PAD + (e % N)];
    }
}

extern "C" void kernel_launch(void* const* d_in, const int* in_sizes, int n_in,
                              void* d_out, int out_size, void* d_ws, size_t ws_size,
                              hipStream_t stream) {
    const float* A = (const float*)d_in[0];     // A_gt, 96*96
    const float* vec = (const float*)d_in[1];   // vec_logits, 4560
    float* out = (float*)d_out;
    k_fused<<<1, T, 0, stream>>>(A, vec, out);
}

// Round 9
// 593.999 us; speedup vs baseline: 1.4733x; 1.0899x over previous
//
#include <hip/hip_runtime.h>
#include <math.h>

#define N 96
#define PAD 100        // padded LDS row stride (floats)
#define T 768          // 12 waves, one workgroup, one CU
#define ITERS 50
#define LW 52          // neighbor-list width (u16 entries, padded to x4)

typedef float f2 __attribute__((ext_vector_type(2)));
typedef unsigned short u16x4 __attribute__((ext_vector_type(4)));

// quad-lane max via DPP (VALU pipe, no LDS traffic); CTRL must be constexpr
template <int CTRL>
__device__ __forceinline__ float dppmax(float m) {
    int mi = __builtin_bit_cast(int, m);
    int sw = __builtin_amdgcn_update_dpp(mi, mi, CTRL, 0xf, 0xf, true);
    return fmaxf(m, __builtin_bit_cast(float, sw));
}
#define DPP_XOR1 0xB1  // quad_perm:[1,0,3,2]
#define DPP_XOR2 0x4E  // quad_perm:[2,3,0,1]

// Fully fused MPM, one workgroup, 3 barriers/iter.
// M-phase: t=(p<<2)|q : q=b-quarter (24 b), ap=p%48 -> cols a0=2ap,a0+1,
//          g=p/48 -> rows j≡g (mod 4), 24 rows. W as float2 pairs (48 regs),
//          products via packed v_pk_mul_f32 + v_max3_f32, DPP quad combine.
// Agg:     ac=t%48 -> cols 2ac,2ac+1 ; rows i = t/48 + 16k (k=0..5);
//          float2 neighbor gathers via byte-offset lists; diag X in regs.
__global__ __launch_bounds__(T)
__attribute__((amdgpu_waves_per_eu(3, 3)))
void k_fused(const float* __restrict__ A,
             const float* __restrict__ vec,
             float* __restrict__ out) {
    __shared__ float Xs[N * PAD];            // 38400 B : X (staging B, then A)
    __shared__ float Ms[(N + 1) * PAD];      // 38800 B : full M + zero row 96
    __shared__ unsigned short lst[N * LW];   //  9984 B : nbr BYTE offsets (j*400)
    __shared__ short cnt4[N];                // padded counts (multiple of 4)
    __shared__ float degA[N];
    __shared__ float degB[N];
    __shared__ float red[T / 64];

    const int t = threadIdx.x;
    const int q = t & 3;                   // b-quarter
    const int p = t >> 2;
    const int ap = p % 48;                 // column-pair id (M-phase)
    const int g = p / 48;                  // row group 0..3
    const int a0 = 2 * ap;
    const int ac = t % 48;                 // column-pair id (agg)
    const int ri = t / 48;                 // agg row base 0..15
    const float s1 = 1.0f / (1.0f + expf(-1.0f));   // sigmoid(1) = diag of B
    const float s1s1 = s1 * s1;

    // ---- setup phase 0: B -> Xs (staging) ----
#pragma unroll
    for (int k = 0; k < 12; ++k) {
        int e = t + k * T;
        int r = e / N, c = e % N;
        float logit;
        if (r == c) {
            logit = 1.0f;
        } else {
            int i = r < c ? r : c;
            int j = r < c ? c : r;
            int idx = i * 95 - (i * (i - 1)) / 2 + (j - i - 1);
            logit = vec[idx];
        }
        Xs[r * PAD + c] = 1.0f / (1.0f + expf(-logit));
    }
    __syncthreads();

    // W quarter-columns as float2 pairs (B symmetric: col a == row a), diag=0
    f2 Wp0[12], Wp1[12];
#pragma unroll
    for (int k = 0; k < 12; ++k) {
        int b = 24 * q + 2 * k;
        float w00 = Xs[b * PAD + a0] * s1s1;
        float w01 = Xs[(b + 1) * PAD + a0] * s1s1;
        float w10 = Xs[b * PAD + a0 + 1] * s1s1;
        float w11 = Xs[(b + 1) * PAD + a0 + 1] * s1s1;
        if (b == a0) w00 = 0.0f;
        if (b + 1 == a0) w01 = 0.0f;
        if (b == a0 + 1) w10 = 0.0f;
        if (b + 1 == a0 + 1) w11 = 0.0f;
        Wp0[k] = (f2){w00, w01};
        Wp1[k] = (f2){w10, w11};
    }

    if (t < N) {
        float s = 0.f;
        for (int r = 0; r < N; ++r) s += Xs[r * PAD + t];
        degB[t] = s;
    }
    __syncthreads();   // all reads of B done

    // ---- setup phase 1: A -> Xs (staging) ----
#pragma unroll
    for (int k = 0; k < 12; ++k) {
        int e = t + k * T;
        Xs[(e / N) * PAD + (e % N)] = A[e];
    }
    __syncthreads();

    if (t < N) {
        float s = 0.f;
        for (int r = 0; r < N; ++r) s += Xs[r * PAD + t];   // A symmetric
        degA[t] = s;
    } else if (t < 2 * N) {
        int i = t - N;
        int c_ = 0;
        for (int j = 0; j < N; ++j) {
            if (j != i && Xs[j * PAD + i] > 0.5f)            // A symmetric
                lst[i * LW + c_++] = (unsigned short)(j * PAD * 4);
        }
        while (c_ & 3) lst[i * LW + c_++] = (unsigned short)(N * PAD * 4);
        cnt4[i] = (short)c_;
    }
    // zero row 96 of Ms (pad target) — written once, never overwritten
    if (t < PAD) Ms[N * PAD + t] = 0.0f;
    __syncthreads();   // lists/degs ready, Xs(A) reads done

    // node-sim coefficients + register-resident diag X (agg map: 6 rows x 2 cols)
    f2 ns2[6], x2[6];
#pragma unroll
    for (int k = 0; k < 6; ++k) {
        int i = ri + 16 * k;
        ns2[k] = (f2){s1 / (fabsf(degA[i] - degB[2 * ac]) + 1.0f),
                      s1 / (fabsf(degA[i] - degB[2 * ac + 1]) + 1.0f)};
        x2[k] = (f2){1.0f / 96.0f, 1.0f / 96.0f};
    }

    // X0 = 1/96 everywhere (||X0|| = 1 exactly)
#pragma unroll
    for (int k = 0; k < 12; ++k) {
        int e = t + k * T;
        Xs[(e / N) * PAD + (e % N)] = (1.0f / 96.0f);
    }
    __syncthreads();

    const float* xbase = &Xs[g * PAD + 24 * q];      // row jj -> + jj*4*PAD
    const char* MsaB = (const char*)Ms + 8 * ac;     // agg col-pair base (bytes)

    // ---- main loop ----
    for (int it = 0; it < ITERS; ++it) {
        // M-phase: 24 rows j = 4*jj + g, const-offset ds reads
#pragma unroll 6
        for (int jj = 0; jj < 24; ++jj) {
            const float* xr = xbase + jj * 4 * PAD;
            float m0 = 0.f, m1 = 0.f;
#pragma unroll
            for (int c = 0; c < 6; ++c) {
                float4 x = *(const float4*)(xr + 4 * c);
                f2 xA = (f2){x.x, x.y};
                f2 xB = (f2){x.z, x.w};
                f2 pa = Wp0[2 * c] * xA;        // v_pk_mul_f32
                f2 pb = Wp0[2 * c + 1] * xB;
                m0 = fmaxf(fmaxf(m0, pa.x), pa.y);   // v_max3_f32
                m0 = fmaxf(fmaxf(m0, pb.x), pb.y);
                f2 qa = Wp1[2 * c] * xA;
                f2 qb = Wp1[2 * c + 1] * xB;
                m1 = fmaxf(fmaxf(m1, qa.x), qa.y);
                m1 = fmaxf(fmaxf(m1, qb.x), qb.y);
            }
            // combine b-quarters across the lane quad on the VALU pipe (exact)
            m0 = dppmax<DPP_XOR1>(m0);
            m0 = dppmax<DPP_XOR2>(m0);
            m1 = dppmax<DPP_XOR1>(m1);
            m1 = dppmax<DPP_XOR2>(m1);
            if (q == 0)
                *(float2*)&Ms[(4 * jj + g) * PAD + a0] = make_float2(m0, m1);
        }
        __syncthreads();   // (A) Ms complete; all Xs reads done

        // aggregate (diag from regs, then ascending-j neighbors — exact order)
        f2 y2[6];
#pragma unroll
        for (int k = 0; k < 6; ++k) {
            int i = ri + 16 * k;
            f2 acc = x2[k] * ns2[k];
            int nch = (int)cnt4[i] >> 2;
            const unsigned short* lp = &lst[i * LW];
            for (int cc = 0; cc < nch; ++cc) {
                u16x4 o = *(const u16x4*)(lp + 4 * cc);
                acc += *(const f2*)(MsaB + o.x);
                acc += *(const f2*)(MsaB + o.y);
                acc += *(const f2*)(MsaB + o.z);
                acc += *(const f2*)(MsaB + o.w);
            }
            y2[k] = acc;
        }

        // block-wide norm (deterministic fixed tree)
        float ss = 0.f;
#pragma unroll
        for (int k = 0; k < 6; ++k) {
            ss = fmaf(y2[k].x, y2[k].x, ss);
            ss = fmaf(y2[k].y, y2[k].y, ss);
        }
#pragma unroll
        for (int mm = 1; mm < 64; mm <<= 1) ss += __shfl_xor(ss, mm, 64);
        if ((t & 63) == 0) red[t >> 6] = ss;
        __syncthreads();   // (B) red ready; all Ms reads done
        float s = 0.f;
#pragma unroll
        for (int w2 = 0; w2 < T / 64; ++w2) s += red[w2];
        float inv = 1.0f / sqrtf(s);
        f2 inv2 = (f2){inv, inv};
#pragma unroll
        for (int k = 0; k < 6; ++k) {
            int i = ri + 16 * k;
            f2 xn = y2[k] * inv2;
            x2[k] = xn;
            *(f2*)&Xs[i * PAD + 2 * ac] = xn;
        }
        __syncthreads();   // (C) Xs ready for next iter; Ms safe to overwrite
    }

    // ---- output ----
#pragma unroll
    for (int k = 0; k < 12; ++k) {
        int e = t + k * T;
        out[e] = Xs[(e / N) * PAD + (e % N)];
    }
}

extern "C" void kernel_launch(void* const* d_in, const int* in_sizes, int n_in,
                              void* d_out, int out_size, void* d_ws, size_t ws_size,
                              hipStream_t stream) {
    const float* A = (const float*)d_in[0];     // A_gt, 96*96
    const float* vec = (const float*)d_in[1];   // vec_logits, 4560
    float* out = (float*)d_out;
    k_fused<<<1, T, 0, stream>>>(A, vec, out);
}